// Round 6
// baseline (1056.464 us; speedup 1.0000x reference)
//
#include <hip/hip_runtime.h>
#include <hip/hip_bf16.h>
#include <stdint.h>

// Problem dims
#define B_SZ 32
#define T_SZ 512
#define I_SZ 1024
#define H_SZ 8
#define HS_SZ 128

typedef __attribute__((ext_vector_type(8))) short short8;
typedef __attribute__((ext_vector_type(4))) float f32x4;

// ---------------- fp32 <-> bf16 helpers ----------------
static __device__ __forceinline__ unsigned short f2bf(float f) {
  union { float f; unsigned int u; } c; c.f = f;
  unsigned int u = c.u;
  unsigned int r = (u + 0x7fffu + ((u >> 16) & 1u)) >> 16;
  return (unsigned short)r;
}
static __device__ __forceinline__ float bf2f(unsigned short s) {
  union { unsigned int u; float f; } c; c.u = ((unsigned int)s) << 16;
  return c.f;
}
// split x into hi (bf16) + lo (bf16 of residual)
static __device__ __forceinline__ void split2(float x, unsigned short& hi,
                                              unsigned short& lo) {
  hi = f2bf(x);
  lo = f2bf(x - bf2f(hi));
}

__global__ void conv_x_split(const float* __restrict__ x,
                             unsigned short* __restrict__ ohi,
                             unsigned short* __restrict__ olo, int n4) {
  int i = blockIdx.x * blockDim.x + threadIdx.x;
  if (i >= n4) return;
  float4 v = ((const float4*)x)[i];
  ushort4 h, l;
  split2(v.x, h.x, l.x);
  split2(v.y, h.y, l.y);
  split2(v.z, h.z, l.z);
  split2(v.w, h.w, l.w);
  ((ushort4*)ohi)[i] = h;
  ((ushort4*)olo)[i] = l;
}

// Combined weight Wc[4096][1024], row n = h*512 + k4:
//   k4 in [0,256)   -> weight_if[h][k4][:]      (i rows then f rows)
//   k4 in [256,512) -> weight_zo[h][k4-256][:]  (z rows then o rows)
__global__ void conv_w_split(const float* __restrict__ wif,
                             const float* __restrict__ wzo,
                             unsigned short* __restrict__ ohi,
                             unsigned short* __restrict__ olo) {
  int i = blockIdx.x * blockDim.x + threadIdx.x;  // float4 index
  int flat = i * 4;
  int n = flat >> 10;
  int col = flat & 1023;
  int h = n >> 9, k4 = n & 511;
  const float* src = (k4 < 256)
                         ? (wif + ((size_t)(h * 256 + k4) * 1024 + col))
                         : (wzo + ((size_t)(h * 256 + (k4 - 256)) * 1024 + col));
  float4 v = *(const float4*)src;
  ushort4 hh, ll;
  split2(v.x, hh.x, ll.x);
  split2(v.y, hh.y, ll.y);
  split2(v.z, hh.z, ll.z);
  split2(v.w, hh.w, ll.w);
  ((ushort4*)ohi)[i] = hh;
  ((ushort4*)olo)[i] = ll;
}

// ---------------- GEMM (3-pass split bf16 = emulated fp32) ----------------
// G[32*tch x 4096] = A_chunk[32*tch x 1024] * Wc^T, acc += AhWh + AhWl + AlWh.
__device__ __forceinline__ void gld_lds16(const void* g, void* l) {
  __builtin_amdgcn_global_load_lds(
      (const __attribute__((address_space(1))) void*)g,
      (__attribute__((address_space(3))) void*)l, 16, 0, 0);
}

__global__ __launch_bounds__(256)
void gemm3_kernel(const unsigned short* __restrict__ Ahi,
                  const unsigned short* __restrict__ Alo,
                  const unsigned short* __restrict__ Whi,
                  const unsigned short* __restrict__ Wlo,
                  float* __restrict__ G, int t0, int ltch) {
  __shared__ short AH[128 * 32];
  __shared__ short AL[128 * 32];
  __shared__ short WH[128 * 32];
  __shared__ short WL[128 * 32];

  int tid = threadIdx.x;
  int lane = tid & 63, wave = tid >> 6;
  int wm = wave >> 1, wn = wave & 1;
  int bx = blockIdx.x, by = blockIdx.y;
  int l15 = lane & 15, kg = lane >> 4;
  int tchm = (1 << ltch) - 1;

  f32x4 zero4 = {0.f, 0.f, 0.f, 0.f};
  f32x4 acc[4][4];
#pragma unroll
  for (int mi = 0; mi < 4; ++mi)
#pragma unroll
    for (int ni = 0; ni < 4; ++ni) acc[mi][ni] = zero4;

  int u0 = wave * 128 + lane;
  int u1 = u0 + 64;
  int r0 = bx * 128 + (u0 >> 2);
  int r1 = bx * 128 + (u1 >> 2);
  size_t arow0 = (size_t)(r0 >> ltch) * 512 + t0 + (r0 & tchm);
  size_t arow1 = (size_t)(r1 >> ltch) * 512 + t0 + (r1 & tchm);
  size_t aoff0 = arow0 * 1024 + (u0 & 3) * 8;
  size_t aoff1 = arow1 * 1024 + (u1 & 3) * 8;
  size_t woff0 = (size_t)(by * 128 + (u0 >> 2)) * 1024 + (u0 & 3) * 8;
  size_t woff1 = (size_t)(by * 128 + (u1 >> 2)) * 1024 + (u1 & 3) * 8;

  short* ah_d0 = &AH[wave * 1024];
  short* ah_d1 = &AH[wave * 1024 + 512];
  short* al_d0 = &AL[wave * 1024];
  short* al_d1 = &AL[wave * 1024 + 512];
  short* wh_d0 = &WH[wave * 1024];
  short* wh_d1 = &WH[wave * 1024 + 512];
  short* wl_d0 = &WL[wave * 1024];
  short* wl_d1 = &WL[wave * 1024 + 512];

  for (int k0 = 0; k0 < 1024; k0 += 32) {
    __syncthreads();
    gld_lds16(Ahi + aoff0 + k0, ah_d0);
    gld_lds16(Ahi + aoff1 + k0, ah_d1);
    gld_lds16(Alo + aoff0 + k0, al_d0);
    gld_lds16(Alo + aoff1 + k0, al_d1);
    gld_lds16(Whi + woff0 + k0, wh_d0);
    gld_lds16(Whi + woff1 + k0, wh_d1);
    gld_lds16(Wlo + woff0 + k0, wl_d0);
    gld_lds16(Wlo + woff1 + k0, wl_d1);
    __syncthreads();

    short8 ah[4], al[4], wh[4], wl[4];
#pragma unroll
    for (int mi = 0; mi < 4; ++mi) {
      int ro = (wm * 64 + mi * 16 + l15) * 32 + kg * 8;
      ah[mi] = *(const short8*)&AH[ro];
      al[mi] = *(const short8*)&AL[ro];
    }
#pragma unroll
    for (int ni = 0; ni < 4; ++ni) {
      int ro = (wn * 64 + ni * 16 + l15) * 32 + kg * 8;
      wh[ni] = *(const short8*)&WH[ro];
      wl[ni] = *(const short8*)&WL[ro];
    }

#pragma unroll
    for (int mi = 0; mi < 4; ++mi)
#pragma unroll
      for (int ni = 0; ni < 4; ++ni) {
        acc[mi][ni] = __builtin_amdgcn_mfma_f32_16x16x32_bf16(
            ah[mi], wh[ni], acc[mi][ni], 0, 0, 0);
        acc[mi][ni] = __builtin_amdgcn_mfma_f32_16x16x32_bf16(
            ah[mi], wl[ni], acc[mi][ni], 0, 0, 0);
        acc[mi][ni] = __builtin_amdgcn_mfma_f32_16x16x32_bf16(
            al[mi], wh[ni], acc[mi][ni], 0, 0, 0);
      }
  }

  // C/D layout (m89-verified): col = lane&15, row = (lane>>4)*4 + reg
#pragma unroll
  for (int mi = 0; mi < 4; ++mi)
#pragma unroll
    for (int ni = 0; ni < 4; ++ni)
#pragma unroll
      for (int r = 0; r < 4; ++r) {
        int grow = bx * 128 + wm * 64 + mi * 16 + kg * 4 + r;
        int gcol = by * 128 + wn * 64 + ni * 16 + l15;
        G[(size_t)grow * 4096 + gcol] = acc[mi][ni][r];
      }
}

// ---------------- Recurrence ----------------
// 256 blocks (one per (b,h)) x 512 threads (8 waves, 2/SIMD).
// Thread t = p*128 + e owns the 32-col slice [32p,32p+32) of W_hh rows
// {e,128+e,256+e,384+e} as 128 scalar fp32 regs (resident in unified
// VGPR/AGPR file — round-5 post-mortem: no spill traffic, direct AGPR
// sourcing; arch-VGPR count of 88 is expected and fine).
//
// Round-6 change: the gate phase previously ran on threads 0..127 only
// (waves 0,1) -> 2 of 4 SIMDs idle every step (VALUBusy 45%). Now ALL
// threads compute the gate chain redundantly per p-group (deterministic,
// identical inputs -> identical c/n/m copies); only p==0 writes h/out.
// Partials: float4 per (p,e) -> 1 ds_write_b128 / 4 ds_read_b128,
// conflict-free (16B lane stride). G loaded by all threads at matvec
// start (coalesced, L2/L3-resident), consumed after the barrier.
__global__ __launch_bounds__(512, 1)
void recur_kernel(const float* __restrict__ G,     // [32*tch, 4096] chunk
                  const float* __restrict__ Whh,   // [8,512,128]
                  const float* __restrict__ bias,  // [8,512]
                  float* __restrict__ out,         // [32,512,1024]
                  float* __restrict__ state,       // 4 x [32,8,128]
                  int t0, int tch, int first) {
  int blk = blockIdx.x;
  int b = blk >> 3, h = blk & 7;
  int t = threadIdx.x;
  int e = t & 127;  // element
  int p = t >> 7;   // col-slice

  __shared__ __align__(16) float hbuf[2][128];
  __shared__ __align__(16) float part_s[4 * 128 * 4];  // [(p*128+e)][gate]

  // own W slice as 128 scalars: wreg[g*32 + c] = W_hh[h][g*128+e][32p + c]
  float wreg[128];
  const float* wbase = Whh + (size_t)h * 65536 + (size_t)p * 32;
#pragma unroll
  for (int g = 0; g < 4; ++g) {
    const float4* wp = (const float4*)(wbase + (size_t)(g * 128 + e) * 128);
#pragma unroll
    for (int q = 0; q < 8; ++q) {
      float4 v = wp[q];
      wreg[g * 32 + q * 4 + 0] = v.x;
      wreg[g * 32 + q * 4 + 1] = v.y;
      wreg[g * 32 + q * 4 + 2] = v.z;
      wreg[g * 32 + q * 4 + 3] = v.w;
    }
  }
#pragma unroll
  for (int i = 0; i < 128; ++i)
    asm volatile("" : "+v"(wreg[i]));  // opaque def: not remat-able

  // per-thread gate constants (same for all p-groups of an e)
  float bj0 = bias[h * 512 + e];
  float bj1 = bias[h * 512 + 128 + e];
  float bj2 = bias[h * 512 + 256 + e];
  float bj3 = bias[h * 512 + 384 + e];

  float c_r = 0.f, n_r = 0.f, m_r = 0.f;
  int si = (b * 8 + h) * 128 + e;
  if (!first) {
    c_r = state[32768 + si];
    m_r = state[65536 + si];
    n_r = state[98304 + si];
  }
  if (t < 128) {
    hbuf[0][e] = first ? 0.f : state[si];
  }
  __syncthreads();

  const float* gpb = G + (size_t)(b * tch) * 4096 + h * 512 + e;
  float* op = out + ((size_t)b * 512 + t0) * 1024 + h * 128 + e;

  int cur = 0;
  for (int s = 0; s < tch; ++s) {
    // ---- G loads for THIS step (consumed after barrier; latency hidden
    //      under the matvec). Coalesced per wave; L2/L3-resident.
    const float* gr = gpb + (size_t)s * 4096;
    float g0 = gr[0];
    float g1 = gr[128];
    float g2 = gr[256];
    float g3 = gr[384];

    // ---- matvec phase (all 512 threads); h reads are wave-uniform ----
    const float4* hv = (const float4*)&hbuf[cur][p * 32];
    float a0 = 0.f, a1 = 0.f, a2 = 0.f, a3 = 0.f;
#pragma unroll
    for (int q = 0; q < 8; ++q) {
      float4 h4 = hv[q];
      a0 = fmaf(wreg[q * 4 + 0], h4.x, a0);
      a0 = fmaf(wreg[q * 4 + 1], h4.y, a0);
      a0 = fmaf(wreg[q * 4 + 2], h4.z, a0);
      a0 = fmaf(wreg[q * 4 + 3], h4.w, a0);
      a1 = fmaf(wreg[32 + q * 4 + 0], h4.x, a1);
      a1 = fmaf(wreg[32 + q * 4 + 1], h4.y, a1);
      a1 = fmaf(wreg[32 + q * 4 + 2], h4.z, a1);
      a1 = fmaf(wreg[32 + q * 4 + 3], h4.w, a1);
      a2 = fmaf(wreg[64 + q * 4 + 0], h4.x, a2);
      a2 = fmaf(wreg[64 + q * 4 + 1], h4.y, a2);
      a2 = fmaf(wreg[64 + q * 4 + 2], h4.z, a2);
      a2 = fmaf(wreg[64 + q * 4 + 3], h4.w, a2);
      a3 = fmaf(wreg[96 + q * 4 + 0], h4.x, a3);
      a3 = fmaf(wreg[96 + q * 4 + 1], h4.y, a3);
      a3 = fmaf(wreg[96 + q * 4 + 2], h4.z, a3);
      a3 = fmaf(wreg[96 + q * 4 + 3], h4.w, a3);
    }
    float4 pv = {a0, a1, a2, a3};
    *(float4*)&part_s[(p * 128 + e) * 4] = pv;
    __syncthreads();

    // ---- gate phase: ALL threads, redundant per p-group ----
    float4 q0 = *(const float4*)&part_s[(0 * 128 + e) * 4];
    float4 q1 = *(const float4*)&part_s[(1 * 128 + e) * 4];
    float4 q2 = *(const float4*)&part_s[(2 * 128 + e) * 4];
    float4 q3 = *(const float4*)&part_s[(3 * 128 + e) * 4];
    float iv = bj0 + g0 + ((q0.x + q1.x) + (q2.x + q3.x));
    float fv = bj1 + g1 + ((q0.y + q1.y) + (q2.y + q3.y));
    float zv = bj2 + g2 + ((q0.z + q1.z) + (q2.z + q3.z));
    float ov = bj3 + g3 + ((q0.w + q1.w) + (q2.w + q3.w));
    float e2 = __expf(2.f * zv);
    float zt = 1.f - 2.f / (e2 + 1.f);       // tanh, inf-safe
    float og = 1.f / (1.f + __expf(-ov));    // sigmoid
    float mn = fmaxf(fv + m_r, iv);
    float ie = __expf(iv - mn);
    float fe = __expf(fv + m_r - mn);
    c_r = fe * c_r + ie * zt;
    n_r = fe * n_r + ie;
    m_r = mn;
    float hnew = og * (c_r / n_r);
    if (t < 128) {
      hbuf[cur ^ 1][e] = hnew;
      op[(size_t)s * 1024] = hnew;
    }
    __syncthreads();
    cur ^= 1;
  }

  if (t < 128) {
    state[si] = hbuf[cur][e];
    state[32768 + si] = c_r;
    state[65536 + si] = m_r;
    state[98304 + si] = n_r;
  }
}

// ---------------- launch ----------------
extern "C" void kernel_launch(void* const* d_in, const int* in_sizes, int n_in,
                              void* d_out, int out_size, void* d_ws, size_t ws_size,
                              hipStream_t stream) {
  const float* xs   = (const float*)d_in[0];
  const float* wif  = (const float*)d_in[1];
  const float* wzo  = (const float*)d_in[2];
  const float* whh  = (const float*)d_in[3];
  const float* bias = (const float*)d_in[4];
  float* out = (float*)d_out;

  char* ws = (char*)d_ws;
  unsigned short* Ahi = (unsigned short*)ws;                 // 33,554,432 B
  unsigned short* Alo = (unsigned short*)(ws + 33554432);    // 33,554,432 B
  unsigned short* Whi = (unsigned short*)(ws + 67108864);    //  8,388,608 B
  unsigned short* Wlo = (unsigned short*)(ws + 75497472);    //  8,388,608 B
  const size_t gbase = 83886080;

  // adaptive time chunk so G fits in ws
  int tch = 128;
  while (tch > 8 &&
         gbase + (size_t)32 * tch * 4096 * 4 + 524288 > ws_size)
    tch >>= 1;
  int ltch = (tch == 128) ? 7 : (tch == 64) ? 6 : (tch == 32) ? 5
             : (tch == 16) ? 4 : 3;

  float* G = (float*)(ws + gbase);
  float* state = (float*)(ws + gbase + (size_t)32 * tch * 4096 * 4);

  conv_x_split<<<16384, 256, 0, stream>>>(xs, Ahi, Alo, 4194304);
  conv_w_split<<<4096, 256, 0, stream>>>(wif, wzo, Whi, Wlo);

  for (int t0 = 0; t0 < 512; t0 += tch) {
    gemm3_kernel<<<dim3(tch / 4, 32), 256, 0, stream>>>(Ahi, Alo, Whi, Wlo,
                                                        G, t0, ltch);
    recur_kernel<<<256, 512, 0, stream>>>(G, whh, bias, out, state, t0, tch,
                                          t0 == 0);
  }
}

// Round 7
// 1015.628 us; speedup vs baseline: 1.0402x; 1.0402x over previous
//
#include <hip/hip_runtime.h>
#include <hip/hip_bf16.h>
#include <stdint.h>

// Problem dims
#define B_SZ 32
#define T_SZ 512
#define I_SZ 1024
#define H_SZ 8
#define HS_SZ 128

typedef __attribute__((ext_vector_type(8))) short short8;
typedef __attribute__((ext_vector_type(4))) float f32x4;

// ---------------- fp32 <-> bf16 helpers ----------------
static __device__ __forceinline__ unsigned short f2bf(float f) {
  union { float f; unsigned int u; } c; c.f = f;
  unsigned int u = c.u;
  unsigned int r = (u + 0x7fffu + ((u >> 16) & 1u)) >> 16;
  return (unsigned short)r;
}
static __device__ __forceinline__ float bf2f(unsigned short s) {
  union { unsigned int u; float f; } c; c.u = ((unsigned int)s) << 16;
  return c.f;
}
static __device__ __forceinline__ void split2(float x, unsigned short& hi,
                                              unsigned short& lo) {
  hi = f2bf(x);
  lo = f2bf(x - bf2f(hi));
}

__global__ void conv_x_split(const float* __restrict__ x,
                             unsigned short* __restrict__ ohi,
                             unsigned short* __restrict__ olo, int n4) {
  int i = blockIdx.x * blockDim.x + threadIdx.x;
  if (i >= n4) return;
  float4 v = ((const float4*)x)[i];
  ushort4 h, l;
  split2(v.x, h.x, l.x);
  split2(v.y, h.y, l.y);
  split2(v.z, h.z, l.z);
  split2(v.w, h.w, l.w);
  ((ushort4*)ohi)[i] = h;
  ((ushort4*)olo)[i] = l;
}

// Combined weight Wc[4096][1024], row n = h*512 + k4:
//   k4 in [0,256)   -> weight_if[h][k4][:]      (i rows then f rows)
//   k4 in [256,512) -> weight_zo[h][k4-256][:]  (z rows then o rows)
__global__ void conv_w_split(const float* __restrict__ wif,
                             const float* __restrict__ wzo,
                             unsigned short* __restrict__ ohi,
                             unsigned short* __restrict__ olo) {
  int i = blockIdx.x * blockDim.x + threadIdx.x;  // float4 index
  int flat = i * 4;
  int n = flat >> 10;
  int col = flat & 1023;
  int h = n >> 9, k4 = n & 511;
  const float* src = (k4 < 256)
                         ? (wif + ((size_t)(h * 256 + k4) * 1024 + col))
                         : (wzo + ((size_t)(h * 256 + (k4 - 256)) * 1024 + col));
  float4 v = *(const float4*)src;
  ushort4 hh, ll;
  split2(v.x, hh.x, ll.x);
  split2(v.y, hh.y, ll.y);
  split2(v.z, hh.z, ll.z);
  split2(v.w, hh.w, ll.w);
  ((ushort4*)ohi)[i] = hh;
  ((ushort4*)olo)[i] = ll;
}

// ---------------- GEMM (3-pass split bf16 = emulated fp32) ----------------
__device__ __forceinline__ void gld_lds16(const void* g, void* l) {
  __builtin_amdgcn_global_load_lds(
      (const __attribute__((address_space(1))) void*)g,
      (__attribute__((address_space(3))) void*)l, 16, 0, 0);
}

__global__ __launch_bounds__(256)
void gemm3_kernel(const unsigned short* __restrict__ Ahi,
                  const unsigned short* __restrict__ Alo,
                  const unsigned short* __restrict__ Whi,
                  const unsigned short* __restrict__ Wlo,
                  float* __restrict__ G, int t0, int ltch) {
  __shared__ short AH[128 * 32];
  __shared__ short AL[128 * 32];
  __shared__ short WH[128 * 32];
  __shared__ short WL[128 * 32];

  int tid = threadIdx.x;
  int lane = tid & 63, wave = tid >> 6;
  int wm = wave >> 1, wn = wave & 1;
  int bx = blockIdx.x, by = blockIdx.y;
  int l15 = lane & 15, kg = lane >> 4;
  int tchm = (1 << ltch) - 1;

  f32x4 zero4 = {0.f, 0.f, 0.f, 0.f};
  f32x4 acc[4][4];
#pragma unroll
  for (int mi = 0; mi < 4; ++mi)
#pragma unroll
    for (int ni = 0; ni < 4; ++ni) acc[mi][ni] = zero4;

  int u0 = wave * 128 + lane;
  int u1 = u0 + 64;
  int r0 = bx * 128 + (u0 >> 2);
  int r1 = bx * 128 + (u1 >> 2);
  size_t arow0 = (size_t)(r0 >> ltch) * 512 + t0 + (r0 & tchm);
  size_t arow1 = (size_t)(r1 >> ltch) * 512 + t0 + (r1 & tchm);
  size_t aoff0 = arow0 * 1024 + (u0 & 3) * 8;
  size_t aoff1 = arow1 * 1024 + (u1 & 3) * 8;
  size_t woff0 = (size_t)(by * 128 + (u0 >> 2)) * 1024 + (u0 & 3) * 8;
  size_t woff1 = (size_t)(by * 128 + (u1 >> 2)) * 1024 + (u1 & 3) * 8;

  short* ah_d0 = &AH[wave * 1024];
  short* ah_d1 = &AH[wave * 1024 + 512];
  short* al_d0 = &AL[wave * 1024];
  short* al_d1 = &AL[wave * 1024 + 512];
  short* wh_d0 = &WH[wave * 1024];
  short* wh_d1 = &WH[wave * 1024 + 512];
  short* wl_d0 = &WL[wave * 1024];
  short* wl_d1 = &WL[wave * 1024 + 512];

  for (int k0 = 0; k0 < 1024; k0 += 32) {
    __syncthreads();
    gld_lds16(Ahi + aoff0 + k0, ah_d0);
    gld_lds16(Ahi + aoff1 + k0, ah_d1);
    gld_lds16(Alo + aoff0 + k0, al_d0);
    gld_lds16(Alo + aoff1 + k0, al_d1);
    gld_lds16(Whi + woff0 + k0, wh_d0);
    gld_lds16(Whi + woff1 + k0, wh_d1);
    gld_lds16(Wlo + woff0 + k0, wl_d0);
    gld_lds16(Wlo + woff1 + k0, wl_d1);
    __syncthreads();

    short8 ah[4], al[4], wh[4], wl[4];
#pragma unroll
    for (int mi = 0; mi < 4; ++mi) {
      int ro = (wm * 64 + mi * 16 + l15) * 32 + kg * 8;
      ah[mi] = *(const short8*)&AH[ro];
      al[mi] = *(const short8*)&AL[ro];
    }
#pragma unroll
    for (int ni = 0; ni < 4; ++ni) {
      int ro = (wn * 64 + ni * 16 + l15) * 32 + kg * 8;
      wh[ni] = *(const short8*)&WH[ro];
      wl[ni] = *(const short8*)&WL[ro];
    }

#pragma unroll
    for (int mi = 0; mi < 4; ++mi)
#pragma unroll
      for (int ni = 0; ni < 4; ++ni) {
        acc[mi][ni] = __builtin_amdgcn_mfma_f32_16x16x32_bf16(
            ah[mi], wh[ni], acc[mi][ni], 0, 0, 0);
        acc[mi][ni] = __builtin_amdgcn_mfma_f32_16x16x32_bf16(
            ah[mi], wl[ni], acc[mi][ni], 0, 0, 0);
        acc[mi][ni] = __builtin_amdgcn_mfma_f32_16x16x32_bf16(
            al[mi], wh[ni], acc[mi][ni], 0, 0, 0);
      }
  }

  // C/D layout (m89-verified): col = lane&15, row = (lane>>4)*4 + reg
#pragma unroll
  for (int mi = 0; mi < 4; ++mi)
#pragma unroll
    for (int ni = 0; ni < 4; ++ni)
#pragma unroll
      for (int r = 0; r < 4; ++r) {
        int grow = bx * 128 + wm * 64 + mi * 16 + kg * 4 + r;
        int gcol = by * 128 + wn * 64 + ni * 16 + l15;
        G[(size_t)grow * 4096 + gcol] = acc[mi][ni][r];
      }
}

// ---------------- Recurrence (round 7: register h + readlane broadcast) ---
// 256 blocks (one per (b,h)) x 512 threads (8 waves).
// Wave pair q = w>>1 owns col-slice [32q,32q+32).
//   matvec: thread (w,l) computes 4 gate partials for em=(w&1)*64+l over its
//           32 cols (weights = 128 resident scalar regs; h via readlane —
//           VALU pipe, ZERO LDS h-traffic).
//   gate:   thread maintains eg = q*32 + (l&31); each wave gates exactly the
//           e-range matching its col-slice, so next step's h[32q+c] is
//           readlane(hreg, c) from its OWN wave. 4 redundant copies (2 lanes
//           x 2 waves), deterministic.
// Partials: part[em*20 + (q^((em>>3)&3))*4 + g] — 16B-aligned b128 r/w,
// XOR-swizzled: writes <=2-way (free), reads conflict-free.
// Double-buffered -> ONE barrier per step.
__global__ __launch_bounds__(512, 1)
void recur_kernel(const float* __restrict__ G,     // [32*tch, 4096] chunk
                  const float* __restrict__ Whh,   // [8,512,128]
                  const float* __restrict__ bias,  // [8,512]
                  float* __restrict__ out,         // [32,512,1024]
                  float* __restrict__ state,       // 4 x [32,8,128]
                  int t0, int tch, int first) {
  int blk = blockIdx.x;
  int b = blk >> 3, h = blk & 7;
  int t = threadIdx.x;
  int w = t >> 6;             // wave 0..7
  int l = t & 63;             // lane
  int q = w >> 1;             // col-slice / pair 0..3
  int em = (w & 1) * 64 + l;  // matvec output element 0..127
  int eg = q * 32 + (l & 31); // gate element this thread maintains

  __shared__ __align__(16) float part[2][128 * 20];  // 20 KB

  // weights: wreg[g*32+c] = Whh[h][g*128+em][32q+c]
  float wreg[128];
  {
    const float* wb = Whh + (size_t)h * 65536 + (size_t)q * 32;
#pragma unroll
    for (int g = 0; g < 4; ++g) {
      const float4* wp = (const float4*)(wb + (size_t)(g * 128 + em) * 128);
#pragma unroll
      for (int c4 = 0; c4 < 8; ++c4) {
        float4 v = wp[c4];
        wreg[g * 32 + c4 * 4 + 0] = v.x;
        wreg[g * 32 + c4 * 4 + 1] = v.y;
        wreg[g * 32 + c4 * 4 + 2] = v.z;
        wreg[g * 32 + c4 * 4 + 3] = v.w;
      }
    }
  }
#pragma unroll
  for (int i = 0; i < 128; ++i)
    asm volatile("" : "+v"(wreg[i]));  // opaque def: keep resident

  int si = (b * 8 + h) * 128 + eg;
  float hreg = 0.f, c_r = 0.f, n_r = 0.f, m_r = 0.f;
  if (!first) {
    hreg = state[si];
    c_r = state[32768 + si];
    m_r = state[65536 + si];
    n_r = state[98304 + si];
  }
  float bj0 = bias[h * 512 + eg];
  float bj1 = bias[h * 512 + 128 + eg];
  float bj2 = bias[h * 512 + 256 + eg];
  float bj3 = bias[h * 512 + 384 + eg];

  const float* gpb = G + (size_t)(b * tch) * 4096 + h * 512 + eg;
  float* op = out + ((size_t)b * 512 + t0) * 1024 + h * 128 + eg;
  bool writer = ((w & 1) == 0) && (l < 32);

  int wslot = (q ^ ((em >> 3) & 3)) * 4;   // write swizzle (constant)
  int ebase = em * 20 + wslot;
  int rb0 = eg * 20 + ((0 ^ ((eg >> 3) & 3)) << 2);
  int rb1 = eg * 20 + ((1 ^ ((eg >> 3) & 3)) << 2);
  int rb2 = eg * 20 + ((2 ^ ((eg >> 3) & 3)) << 2);
  int rb3 = eg * 20 + ((3 ^ ((eg >> 3) & 3)) << 2);

  for (int s = 0; s < tch; ++s) {
    // G for this step — issued first, consumed after the barrier (hidden
    // under the matvec FMAs).
    const float* gr = gpb + (size_t)s * 4096;
    float g0 = gr[0], g1 = gr[128], g2 = gr[256], g3 = gr[384];

    // ---- matvec: h broadcast via readlane (VALU), no LDS ----
    float a0 = 0.f, a1 = 0.f, a2 = 0.f, a3 = 0.f;
    int hbits = __float_as_int(hreg);
#pragma unroll
    for (int c = 0; c < 32; ++c) {
      float hs = __int_as_float(__builtin_amdgcn_readlane(hbits, c));
      a0 = fmaf(wreg[c], hs, a0);
      a1 = fmaf(wreg[32 + c], hs, a1);
      a2 = fmaf(wreg[64 + c], hs, a2);
      a3 = fmaf(wreg[96 + c], hs, a3);
    }
    float4 pv = {a0, a1, a2, a3};
    *(float4*)&part[s & 1][ebase] = pv;
    __syncthreads();

    // ---- gate: all waves, redundant per (lane-half x pair) ----
    float4 p0 = *(const float4*)&part[s & 1][rb0];
    float4 p1 = *(const float4*)&part[s & 1][rb1];
    float4 p2 = *(const float4*)&part[s & 1][rb2];
    float4 p3 = *(const float4*)&part[s & 1][rb3];
    float iv = bj0 + g0 + ((p0.x + p1.x) + (p2.x + p3.x));
    float fv = bj1 + g1 + ((p0.y + p1.y) + (p2.y + p3.y));
    float zv = bj2 + g2 + ((p0.z + p1.z) + (p2.z + p3.z));
    float ov = bj3 + g3 + ((p0.w + p1.w) + (p2.w + p3.w));
    float e2 = __expf(2.f * zv);
    float zt = 1.f - 2.f / (e2 + 1.f);       // tanh, inf-safe
    float og = 1.f / (1.f + __expf(-ov));    // sigmoid
    float mn = fmaxf(fv + m_r, iv);
    float ie = __expf(iv - mn);
    float fe = __expf(fv + m_r - mn);
    c_r = fe * c_r + ie * zt;
    n_r = fe * n_r + ie;
    m_r = mn;
    float hnew = og * (c_r / n_r);
    hreg = hnew;
    if (writer) op[(size_t)s * 1024] = hnew;
    // no second barrier: next step writes the OTHER part buffer; reads of
    // buffer (s-1)&1 happened before barrier(s) in every thread's program
    // order, and write(s+1) happens after barrier(s).
  }

  if (writer) {
    state[si] = hreg;
    state[32768 + si] = c_r;
    state[65536 + si] = m_r;
    state[98304 + si] = n_r;
  }
}

// ---------------- launch ----------------
extern "C" void kernel_launch(void* const* d_in, const int* in_sizes, int n_in,
                              void* d_out, int out_size, void* d_ws, size_t ws_size,
                              hipStream_t stream) {
  const float* xs   = (const float*)d_in[0];
  const float* wif  = (const float*)d_in[1];
  const float* wzo  = (const float*)d_in[2];
  const float* whh  = (const float*)d_in[3];
  const float* bias = (const float*)d_in[4];
  float* out = (float*)d_out;

  char* ws = (char*)d_ws;
  unsigned short* Ahi = (unsigned short*)ws;                 // 33,554,432 B
  unsigned short* Alo = (unsigned short*)(ws + 33554432);    // 33,554,432 B
  unsigned short* Whi = (unsigned short*)(ws + 67108864);    //  8,388,608 B
  unsigned short* Wlo = (unsigned short*)(ws + 75497472);    //  8,388,608 B
  const size_t gbase = 83886080;

  // adaptive time chunk so G fits in ws
  int tch = 128;
  while (tch > 8 &&
         gbase + (size_t)32 * tch * 4096 * 4 + 524288 > ws_size)
    tch >>= 1;
  int ltch = (tch == 128) ? 7 : (tch == 64) ? 6 : (tch == 32) ? 5
             : (tch == 16) ? 4 : 3;

  float* G = (float*)(ws + gbase);
  float* state = (float*)(ws + gbase + (size_t)32 * tch * 4096 * 4);

  conv_x_split<<<16384, 256, 0, stream>>>(xs, Ahi, Alo, 4194304);
  conv_w_split<<<4096, 256, 0, stream>>>(wif, wzo, Whi, Wlo);

  for (int t0 = 0; t0 < 512; t0 += tch) {
    gemm3_kernel<<<dim3(tch / 4, 32), 256, 0, stream>>>(Ahi, Alo, Whi, Wlo,
                                                        G, t0, ltch);
    recur_kernel<<<256, 512, 0, stream>>>(G, whh, bias, out, state, t0, tch,
                                          t0 == 0);
  }
}

// Round 8
// 915.013 us; speedup vs baseline: 1.1546x; 1.1100x over previous
//
#include <hip/hip_runtime.h>
#include <hip/hip_bf16.h>
#include <stdint.h>

// Problem dims
#define B_SZ 32
#define T_SZ 512
#define I_SZ 1024
#define H_SZ 8
#define HS_SZ 128

typedef __attribute__((ext_vector_type(8))) short short8;
typedef __attribute__((ext_vector_type(4))) float f32x4;

// ---------------- fp32 <-> bf16 helpers ----------------
static __device__ __forceinline__ unsigned short f2bf(float f) {
  union { float f; unsigned int u; } c; c.f = f;
  unsigned int u = c.u;
  unsigned int r = (u + 0x7fffu + ((u >> 16) & 1u)) >> 16;
  return (unsigned short)r;
}
static __device__ __forceinline__ float bf2f(unsigned short s) {
  union { unsigned int u; float f; } c; c.u = ((unsigned int)s) << 16;
  return c.f;
}
static __device__ __forceinline__ void split2(float x, unsigned short& hi,
                                              unsigned short& lo) {
  hi = f2bf(x);
  lo = f2bf(x - bf2f(hi));
}

__global__ void conv_x_split(const float* __restrict__ x,
                             unsigned short* __restrict__ ohi,
                             unsigned short* __restrict__ olo, int n4) {
  int i = blockIdx.x * blockDim.x + threadIdx.x;
  if (i >= n4) return;
  float4 v = ((const float4*)x)[i];
  ushort4 h, l;
  split2(v.x, h.x, l.x);
  split2(v.y, h.y, l.y);
  split2(v.z, h.z, l.z);
  split2(v.w, h.w, l.w);
  ((ushort4*)ohi)[i] = h;
  ((ushort4*)olo)[i] = l;
}

// Combined weight Wc[4096][1024], row n = h*512 + k4:
//   k4 in [0,256)   -> weight_if[h][k4][:]      (i rows then f rows)
//   k4 in [256,512) -> weight_zo[h][k4-256][:]  (z rows then o rows)
__global__ void conv_w_split(const float* __restrict__ wif,
                             const float* __restrict__ wzo,
                             unsigned short* __restrict__ ohi,
                             unsigned short* __restrict__ olo) {
  int i = blockIdx.x * blockDim.x + threadIdx.x;  // float4 index
  int flat = i * 4;
  int n = flat >> 10;
  int col = flat & 1023;
  int h = n >> 9, k4 = n & 511;
  const float* src = (k4 < 256)
                         ? (wif + ((size_t)(h * 256 + k4) * 1024 + col))
                         : (wzo + ((size_t)(h * 256 + (k4 - 256)) * 1024 + col));
  float4 v = *(const float4*)src;
  ushort4 hh, ll;
  split2(v.x, hh.x, ll.x);
  split2(v.y, hh.y, ll.y);
  split2(v.z, hh.z, ll.z);
  split2(v.w, hh.w, ll.w);
  ((ushort4*)ohi)[i] = hh;
  ((ushort4*)olo)[i] = ll;
}

// ---------------- GEMM (3-pass split bf16 = emulated fp32) ----------------
__device__ __forceinline__ void gld_lds16(const void* g, void* l) {
  __builtin_amdgcn_global_load_lds(
      (const __attribute__((address_space(1))) void*)g,
      (__attribute__((address_space(3))) void*)l, 16, 0, 0);
}

__global__ __launch_bounds__(256)
void gemm3_kernel(const unsigned short* __restrict__ Ahi,
                  const unsigned short* __restrict__ Alo,
                  const unsigned short* __restrict__ Whi,
                  const unsigned short* __restrict__ Wlo,
                  float* __restrict__ G, int t0, int ltch) {
  __shared__ short AH[128 * 32];
  __shared__ short AL[128 * 32];
  __shared__ short WH[128 * 32];
  __shared__ short WL[128 * 32];

  int tid = threadIdx.x;
  int lane = tid & 63, wave = tid >> 6;
  int wm = wave >> 1, wn = wave & 1;
  int bx = blockIdx.x, by = blockIdx.y;
  int l15 = lane & 15, kg = lane >> 4;
  int tchm = (1 << ltch) - 1;

  f32x4 zero4 = {0.f, 0.f, 0.f, 0.f};
  f32x4 acc[4][4];
#pragma unroll
  for (int mi = 0; mi < 4; ++mi)
#pragma unroll
    for (int ni = 0; ni < 4; ++ni) acc[mi][ni] = zero4;

  int u0 = wave * 128 + lane;
  int u1 = u0 + 64;
  int r0 = bx * 128 + (u0 >> 2);
  int r1 = bx * 128 + (u1 >> 2);
  size_t arow0 = (size_t)(r0 >> ltch) * 512 + t0 + (r0 & tchm);
  size_t arow1 = (size_t)(r1 >> ltch) * 512 + t0 + (r1 & tchm);
  size_t aoff0 = arow0 * 1024 + (u0 & 3) * 8;
  size_t aoff1 = arow1 * 1024 + (u1 & 3) * 8;
  size_t woff0 = (size_t)(by * 128 + (u0 >> 2)) * 1024 + (u0 & 3) * 8;
  size_t woff1 = (size_t)(by * 128 + (u1 >> 2)) * 1024 + (u1 & 3) * 8;

  short* ah_d0 = &AH[wave * 1024];
  short* ah_d1 = &AH[wave * 1024 + 512];
  short* al_d0 = &AL[wave * 1024];
  short* al_d1 = &AL[wave * 1024 + 512];
  short* wh_d0 = &WH[wave * 1024];
  short* wh_d1 = &WH[wave * 1024 + 512];
  short* wl_d0 = &WL[wave * 1024];
  short* wl_d1 = &WL[wave * 1024 + 512];

  for (int k0 = 0; k0 < 1024; k0 += 32) {
    __syncthreads();
    gld_lds16(Ahi + aoff0 + k0, ah_d0);
    gld_lds16(Ahi + aoff1 + k0, ah_d1);
    gld_lds16(Alo + aoff0 + k0, al_d0);
    gld_lds16(Alo + aoff1 + k0, al_d1);
    gld_lds16(Whi + woff0 + k0, wh_d0);
    gld_lds16(Whi + woff1 + k0, wh_d1);
    gld_lds16(Wlo + woff0 + k0, wl_d0);
    gld_lds16(Wlo + woff1 + k0, wl_d1);
    __syncthreads();

    short8 ah[4], al[4], wh[4], wl[4];
#pragma unroll
    for (int mi = 0; mi < 4; ++mi) {
      int ro = (wm * 64 + mi * 16 + l15) * 32 + kg * 8;
      ah[mi] = *(const short8*)&AH[ro];
      al[mi] = *(const short8*)&AL[ro];
    }
#pragma unroll
    for (int ni = 0; ni < 4; ++ni) {
      int ro = (wn * 64 + ni * 16 + l15) * 32 + kg * 8;
      wh[ni] = *(const short8*)&WH[ro];
      wl[ni] = *(const short8*)&WL[ro];
    }

#pragma unroll
    for (int mi = 0; mi < 4; ++mi)
#pragma unroll
      for (int ni = 0; ni < 4; ++ni) {
        acc[mi][ni] = __builtin_amdgcn_mfma_f32_16x16x32_bf16(
            ah[mi], wh[ni], acc[mi][ni], 0, 0, 0);
        acc[mi][ni] = __builtin_amdgcn_mfma_f32_16x16x32_bf16(
            ah[mi], wl[ni], acc[mi][ni], 0, 0, 0);
        acc[mi][ni] = __builtin_amdgcn_mfma_f32_16x16x32_bf16(
            al[mi], wh[ni], acc[mi][ni], 0, 0, 0);
      }
  }

  // C/D layout (m89-verified): col = lane&15, row = (lane>>4)*4 + reg
#pragma unroll
  for (int mi = 0; mi < 4; ++mi)
#pragma unroll
    for (int ni = 0; ni < 4; ++ni)
#pragma unroll
      for (int r = 0; r < 4; ++r) {
        int grow = bx * 128 + wm * 64 + mi * 16 + kg * 4 + r;
        int gcol = by * 128 + wn * 64 + ni * 16 + l15;
        G[(size_t)grow * 4096 + gcol] = acc[mi][ni][r];
      }
}

// ---------------- Recurrence (round 8) ----------------
// Structure as round 7 (register weights, readlane h-broadcast, b128
// partial exchange, 1 barrier/step) with three fixes:
//  1. G prefetched ONE FULL STEP ahead (round-7 postmortem: ~1100 cyc/step
//     of exposed latency; FETCH shows half of G comes from HBM ~900 cyc;
//     same-step prefetch distance (~800 cyc) was marginally too short).
//  2. Partial-exchange XOR dropped: stride-20-float (5xfloat4) already
//     cycles b128 lanes through all 8 bank-quads; the XOR *caused* the
//     8.4M bank conflicts.
//  3. Fast-math gate: v_rcp for sigmoid/tanh denominators and c/n
//     (1-ulp; error budget has 5x margin).
__global__ __launch_bounds__(512, 1)
void recur_kernel(const float* __restrict__ G,     // [32*tch, 4096] chunk
                  const float* __restrict__ Whh,   // [8,512,128]
                  const float* __restrict__ bias,  // [8,512]
                  float* __restrict__ out,         // [32,512,1024]
                  float* __restrict__ state,       // 4 x [32,8,128]
                  int t0, int tch, int first) {
  int blk = blockIdx.x;
  int b = blk >> 3, h = blk & 7;
  int t = threadIdx.x;
  int w = t >> 6;             // wave 0..7
  int l = t & 63;             // lane
  int q = w >> 1;             // col-slice / pair 0..3
  int em = (w & 1) * 64 + l;  // matvec output element 0..127
  int eg = q * 32 + (l & 31); // gate element this thread maintains

  __shared__ __align__(16) float part[2][128 * 20];  // 20 KB

  // weights: wreg[g*32+c] = Whh[h][g*128+em][32q+c]
  float wreg[128];
  {
    const float* wb = Whh + (size_t)h * 65536 + (size_t)q * 32;
#pragma unroll
    for (int g = 0; g < 4; ++g) {
      const float4* wp = (const float4*)(wb + (size_t)(g * 128 + em) * 128);
#pragma unroll
      for (int c4 = 0; c4 < 8; ++c4) {
        float4 v = wp[c4];
        wreg[g * 32 + c4 * 4 + 0] = v.x;
        wreg[g * 32 + c4 * 4 + 1] = v.y;
        wreg[g * 32 + c4 * 4 + 2] = v.z;
        wreg[g * 32 + c4 * 4 + 3] = v.w;
      }
    }
  }
#pragma unroll
  for (int i = 0; i < 128; ++i)
    asm volatile("" : "+v"(wreg[i]));  // opaque def: keep resident

  int si = (b * 8 + h) * 128 + eg;
  float hreg = 0.f, c_r = 0.f, n_r = 0.f, m_r = 0.f;
  if (!first) {
    hreg = state[si];
    c_r = state[32768 + si];
    m_r = state[65536 + si];
    n_r = state[98304 + si];
  }
  float bj0 = bias[h * 512 + eg];
  float bj1 = bias[h * 512 + 128 + eg];
  float bj2 = bias[h * 512 + 256 + eg];
  float bj3 = bias[h * 512 + 384 + eg];

  const float* gpb = G + (size_t)(b * tch) * 4096 + h * 512 + eg;
  float* op = out + ((size_t)b * 512 + t0) * 1024 + h * 128 + eg;
  bool writer = ((w & 1) == 0) && (l < 32);

  int ebase = em * 20 + q * 4;   // write slot (no XOR)
  int rb0 = eg * 20 + 0;
  int rb1 = eg * 20 + 4;
  int rb2 = eg * 20 + 8;
  int rb3 = eg * 20 + 12;

  // G for step 0 (exposed once; every later step is prefetched +1 ahead)
  float g0 = gpb[0], g1 = gpb[128], g2 = gpb[256], g3 = gpb[384];

  for (int s = 0; s < tch; ++s) {
    // ---- prefetch G for step s+1 (consumed at the END of iteration s+1:
    //      ~2 full steps of slack -> HBM latency fully hidden) ----
    float gn0 = 0.f, gn1 = 0.f, gn2 = 0.f, gn3 = 0.f;
    if (s + 1 < tch) {
      const float* gr = gpb + (size_t)(s + 1) * 4096;
      gn0 = gr[0]; gn1 = gr[128]; gn2 = gr[256]; gn3 = gr[384];
    }

    // ---- matvec: h broadcast via readlane (VALU), no LDS ----
    float a0 = 0.f, a1 = 0.f, a2 = 0.f, a3 = 0.f;
    int hbits = __float_as_int(hreg);
#pragma unroll
    for (int c = 0; c < 32; ++c) {
      float hs = __int_as_float(__builtin_amdgcn_readlane(hbits, c));
      a0 = fmaf(wreg[c], hs, a0);
      a1 = fmaf(wreg[32 + c], hs, a1);
      a2 = fmaf(wreg[64 + c], hs, a2);
      a3 = fmaf(wreg[96 + c], hs, a3);
    }
    float4 pv = {a0, a1, a2, a3};
    *(float4*)&part[s & 1][ebase] = pv;
    __syncthreads();

    // ---- gate: all waves, redundant per (lane-half x pair) ----
    float4 p0 = *(const float4*)&part[s & 1][rb0];
    float4 p1 = *(const float4*)&part[s & 1][rb1];
    float4 p2 = *(const float4*)&part[s & 1][rb2];
    float4 p3 = *(const float4*)&part[s & 1][rb3];
    float iv = bj0 + g0 + ((p0.x + p1.x) + (p2.x + p3.x));
    float fv = bj1 + g1 + ((p0.y + p1.y) + (p2.y + p3.y));
    float zv = bj2 + g2 + ((p0.z + p1.z) + (p2.z + p3.z));
    float ov = bj3 + g3 + ((p0.w + p1.w) + (p2.w + p3.w));
    float e2 = __expf(2.f * zv);
    float zt = 1.f - 2.f * __builtin_amdgcn_rcpf(e2 + 1.f);   // tanh
    float og = __builtin_amdgcn_rcpf(1.f + __expf(-ov));      // sigmoid
    float mn = fmaxf(fv + m_r, iv);
    float ie = __expf(iv - mn);
    float fe = __expf(fv + m_r - mn);
    c_r = fe * c_r + ie * zt;
    n_r = fe * n_r + ie;
    m_r = mn;
    float hnew = og * c_r * __builtin_amdgcn_rcpf(n_r);
    hreg = hnew;
    if (writer) op[(size_t)s * 1024] = hnew;
    g0 = gn0; g1 = gn1; g2 = gn2; g3 = gn3;
    // no second barrier: next step writes the OTHER part buffer; write(s+2)
    // to this buffer is separated from read(s) by barrier(s+1).
  }

  if (writer) {
    state[si] = hreg;
    state[32768 + si] = c_r;
    state[65536 + si] = m_r;
    state[98304 + si] = n_r;
  }
}

// ---------------- launch ----------------
extern "C" void kernel_launch(void* const* d_in, const int* in_sizes, int n_in,
                              void* d_out, int out_size, void* d_ws, size_t ws_size,
                              hipStream_t stream) {
  const float* xs   = (const float*)d_in[0];
  const float* wif  = (const float*)d_in[1];
  const float* wzo  = (const float*)d_in[2];
  const float* whh  = (const float*)d_in[3];
  const float* bias = (const float*)d_in[4];
  float* out = (float*)d_out;

  char* ws = (char*)d_ws;
  unsigned short* Ahi = (unsigned short*)ws;                 // 33,554,432 B
  unsigned short* Alo = (unsigned short*)(ws + 33554432);    // 33,554,432 B
  unsigned short* Whi = (unsigned short*)(ws + 67108864);    //  8,388,608 B
  unsigned short* Wlo = (unsigned short*)(ws + 75497472);    //  8,388,608 B
  const size_t gbase = 83886080;

  // adaptive time chunk so G fits in ws
  int tch = 128;
  while (tch > 8 &&
         gbase + (size_t)32 * tch * 4096 * 4 + 524288 > ws_size)
    tch >>= 1;
  int ltch = (tch == 128) ? 7 : (tch == 64) ? 6 : (tch == 32) ? 5
             : (tch == 16) ? 4 : 3;

  float* G = (float*)(ws + gbase);
  float* state = (float*)(ws + gbase + (size_t)32 * tch * 4096 * 4);

  conv_x_split<<<16384, 256, 0, stream>>>(xs, Ahi, Alo, 4194304);
  conv_w_split<<<4096, 256, 0, stream>>>(wif, wzo, Whi, Wlo);

  for (int t0 = 0; t0 < 512; t0 += tch) {
    gemm3_kernel<<<dim3(tch / 4, 32), 256, 0, stream>>>(Ahi, Alo, Whi, Wlo,
                                                        G, t0, ltch);
    recur_kernel<<<256, 512, 0, stream>>>(G, whh, bias, out, state, t0, tch,
                                          t0 == 0);
  }
}

// Round 9
// 822.107 us; speedup vs baseline: 1.2851x; 1.1130x over previous
//
#include <hip/hip_runtime.h>
#include <hip/hip_bf16.h>
#include <stdint.h>

// Problem dims
#define B_SZ 32
#define T_SZ 512
#define I_SZ 1024
#define H_SZ 8
#define HS_SZ 128

typedef __attribute__((ext_vector_type(8))) short short8;
typedef __attribute__((ext_vector_type(4))) float f32x4;

// ---------------- fp32 <-> bf16 helpers ----------------
static __device__ __forceinline__ unsigned short f2bf(float f) {
  union { float f; unsigned int u; } c; c.f = f;
  unsigned int u = c.u;
  unsigned int r = (u + 0x7fffu + ((u >> 16) & 1u)) >> 16;
  return (unsigned short)r;
}
static __device__ __forceinline__ float bf2f(unsigned short s) {
  union { unsigned int u; float f; } c; c.u = ((unsigned int)s) << 16;
  return c.f;
}
static __device__ __forceinline__ void split2(float x, unsigned short& hi,
                                              unsigned short& lo) {
  hi = f2bf(x);
  lo = f2bf(x - bf2f(hi));
}

__global__ void conv_x_split(const float* __restrict__ x,
                             unsigned short* __restrict__ ohi,
                             unsigned short* __restrict__ olo, int n4) {
  int i = blockIdx.x * blockDim.x + threadIdx.x;
  if (i >= n4) return;
  float4 v = ((const float4*)x)[i];
  ushort4 h, l;
  split2(v.x, h.x, l.x);
  split2(v.y, h.y, l.y);
  split2(v.z, h.z, l.z);
  split2(v.w, h.w, l.w);
  ((ushort4*)ohi)[i] = h;
  ((ushort4*)olo)[i] = l;
}

// Combined weight Wc[4096][1024], row n = h*512 + k4:
//   k4 in [0,256)   -> weight_if[h][k4][:]      (i rows then f rows)
//   k4 in [256,512) -> weight_zo[h][k4-256][:]  (z rows then o rows)
__global__ void conv_w_split(const float* __restrict__ wif,
                             const float* __restrict__ wzo,
                             unsigned short* __restrict__ ohi,
                             unsigned short* __restrict__ olo) {
  int i = blockIdx.x * blockDim.x + threadIdx.x;  // float4 index
  int flat = i * 4;
  int n = flat >> 10;
  int col = flat & 1023;
  int h = n >> 9, k4 = n & 511;
  const float* src = (k4 < 256)
                         ? (wif + ((size_t)(h * 256 + k4) * 1024 + col))
                         : (wzo + ((size_t)(h * 256 + (k4 - 256)) * 1024 + col));
  float4 v = *(const float4*)src;
  ushort4 hh, ll;
  split2(v.x, hh.x, ll.x);
  split2(v.y, hh.y, ll.y);
  split2(v.z, hh.z, ll.z);
  split2(v.w, hh.w, ll.w);
  ((ushort4*)ohi)[i] = hh;
  ((ushort4*)olo)[i] = ll;
}

// ---------------- GEMM v2 (round 9) ----------------
// G[32*tch x 4096] = A_chunk[32*tch x 1024] * Wc^T; 3-pass split-bf16
// (AhWh + AhWl + AlWh, fp32 acc — identical arithmetic to round 8).
// New structure: 256x128 tile, BK=32, 8 waves (4M x 2N, wave-tile 64x64),
// double-buffered LDS (2 x 48 KB), counted vmcnt (never 0 in steady state),
// raw s_barrier (avoids compiler's vmcnt(0) drain at __syncthreads — the
// m97-structure ~20% stall), slot-XOR swizzle for conflict-free frag reads,
// setprio around the MFMA cluster.
//
// LDS layout per buffer (shorts): AH[256r x 32k] @0, AL @8192, WH[128r x 32k]
// @16384, WL @20480. Unit = 16 B (8 shorts); LDS[r][j] holds global k-slot
// j ^ ((r>>1)&3) — staged via pre-swizzled per-lane GLOBAL address with a
// linear LDS dest (global_load_lds writes base+lane*16). Frag read for
// k-slot kg reads j = kg ^ ((r>>1)&3): over 16 rows the bank-quads cover
// all 8 quads exactly twice -> 2-way (free, m136).
__device__ __forceinline__ void gld_lds16(const void* g, void* l) {
  __builtin_amdgcn_global_load_lds(
      (const __attribute__((address_space(1))) void*)g,
      (__attribute__((address_space(3))) void*)l, 16, 0, 0);
}

__global__ __launch_bounds__(512)
void gemm3_kernel(const unsigned short* __restrict__ Ahi,
                  const unsigned short* __restrict__ Alo,
                  const unsigned short* __restrict__ Whi,
                  const unsigned short* __restrict__ Wlo,
                  float* __restrict__ G, int t0, int ltch) {
  __shared__ short lds2[2][24576];  // 2 x 48 KB

  const int tid = threadIdx.x;
  const int lane = tid & 63, wv = tid >> 6;
  const int wm = wv >> 1, wn = wv & 1;   // 4 M-waves x 2 N-waves
  const int bx = blockIdx.x, by = blockIdx.y;
  const int l15 = lane & 15, kg = lane >> 4;
  const int tchm = (1 << ltch) - 1;

  // ---- staging source pointers (6 units of 16 B per thread per K-step) ----
  // unit u = tid + t*512: t=0,1 -> AH; t=2,3 -> AL; t=4 -> WH; t=5 -> WL
  const unsigned short* gsrc[6];
#pragma unroll
  for (int t = 0; t < 6; ++t) {
    int u = tid + t * 512;
    int j = u & 3;
    if (t < 4) {
      int r = (u >> 2) & 255;
      int gslot = j ^ ((r >> 1) & 3);
      int cr = bx * 256 + r;
      size_t xsrow = (size_t)(cr >> ltch) * 512 + t0 + (cr & tchm);
      gsrc[t] = ((t < 2) ? Ahi : Alo) + xsrow * 1024 + gslot * 8;
    } else {
      int r = (u >> 2) & 127;
      int gslot = j ^ ((r >> 1) & 3);
      size_t wr = (size_t)by * 128 + r;
      gsrc[t] = ((t == 4) ? Whi : Wlo) + wr * 1024 + gslot * 8;
    }
  }

  // ---- frag read offsets (shorts), swizzled slot per row ----
  int offa[4], offw[4];
#pragma unroll
  for (int mi = 0; mi < 4; ++mi) {
    int r = wm * 64 + mi * 16 + l15;
    offa[mi] = r * 32 + (kg ^ ((r >> 1) & 3)) * 8;
  }
#pragma unroll
  for (int ni = 0; ni < 4; ++ni) {
    int r = wn * 64 + ni * 16 + l15;
    offw[ni] = r * 32 + (kg ^ ((r >> 1) & 3)) * 8;
  }

  f32x4 zero4 = {0.f, 0.f, 0.f, 0.f};
  f32x4 acc[4][4];
#pragma unroll
  for (int mi = 0; mi < 4; ++mi)
#pragma unroll
    for (int ni = 0; ni < 4; ++ni) acc[mi][ni] = zero4;

  // ---- prologue: stage K-steps 0 and 1 ----
#pragma unroll
  for (int t = 0; t < 6; ++t)
    gld_lds16(gsrc[t], &lds2[0][(wv * 64 + t * 512) * 8]);
#pragma unroll
  for (int t = 0; t < 6; ++t)
    gld_lds16(gsrc[t] + 32, &lds2[1][(wv * 64 + t * 512) * 8]);
  asm volatile("s_waitcnt vmcnt(6)" : : : "memory");  // stage(0) landed
  __builtin_amdgcn_s_barrier();

  // ---- main loop: 32 K-steps ----
  for (int ks = 0; ks < 32; ++ks) {
    const short* bp = &lds2[ks & 1][0];

    short8 ah[4], wh4[4], al[4], wl4[4];
#pragma unroll
    for (int mi = 0; mi < 4; ++mi) ah[mi] = *(const short8*)(bp + offa[mi]);
#pragma unroll
    for (int ni = 0; ni < 4; ++ni)
      wh4[ni] = *(const short8*)(bp + 16384 + offw[ni]);

    __builtin_amdgcn_s_setprio(1);
#pragma unroll
    for (int mi = 0; mi < 4; ++mi)
#pragma unroll
      for (int ni = 0; ni < 4; ++ni)
        acc[mi][ni] = __builtin_amdgcn_mfma_f32_16x16x32_bf16(
            ah[mi], wh4[ni], acc[mi][ni], 0, 0, 0);

#pragma unroll
    for (int mi = 0; mi < 4; ++mi)
      al[mi] = *(const short8*)(bp + 8192 + offa[mi]);
#pragma unroll
    for (int mi = 0; mi < 4; ++mi)
#pragma unroll
      for (int ni = 0; ni < 4; ++ni)
        acc[mi][ni] = __builtin_amdgcn_mfma_f32_16x16x32_bf16(
            al[mi], wh4[ni], acc[mi][ni], 0, 0, 0);

#pragma unroll
    for (int ni = 0; ni < 4; ++ni)
      wl4[ni] = *(const short8*)(bp + 20480 + offw[ni]);
#pragma unroll
    for (int mi = 0; mi < 4; ++mi)
#pragma unroll
      for (int ni = 0; ni < 4; ++ni)
        acc[mi][ni] = __builtin_amdgcn_mfma_f32_16x16x32_bf16(
            ah[mi], wl4[ni], acc[mi][ni], 0, 0, 0);
    __builtin_amdgcn_s_setprio(0);

    // all this wave's reads of buf[ks&1] are complete (MFMA consumed them)
    asm volatile("s_waitcnt lgkmcnt(0)" : : : "memory");
    __builtin_amdgcn_sched_barrier(0);
    __builtin_amdgcn_s_barrier();  // block-wide: buf[ks&1] free to overwrite

    if (ks + 2 < 32) {
      // stage(ks+2) into buf[ks&1]; then retire stage(ks+1) (6 newest stay
      // in flight across the barrier — never vmcnt(0) in steady state)
#pragma unroll
      for (int t = 0; t < 6; ++t)
        gld_lds16(gsrc[t] + (ks + 2) * 32,
                  &lds2[ks & 1][(wv * 64 + t * 512) * 8]);
      asm volatile("s_waitcnt vmcnt(6)" : : : "memory");
    } else {
      asm volatile("s_waitcnt vmcnt(0)" : : : "memory");
    }
    __builtin_amdgcn_s_barrier();  // buf[(ks+1)&1] ready for all waves
  }

  // ---- epilogue: C/D layout (m89): col = lane&15, row = (lane>>4)*4+reg ----
#pragma unroll
  for (int mi = 0; mi < 4; ++mi)
#pragma unroll
    for (int ni = 0; ni < 4; ++ni)
#pragma unroll
      for (int r = 0; r < 4; ++r) {
        int grow = bx * 256 + wm * 64 + mi * 16 + kg * 4 + r;
        int gcol = by * 128 + wn * 64 + ni * 16 + l15;
        G[(size_t)grow * 4096 + gcol] = acc[mi][ni][r];
      }
}

// ---------------- Recurrence (unchanged from round 8) ----------------
__global__ __launch_bounds__(512, 1)
void recur_kernel(const float* __restrict__ G,     // [32*tch, 4096] chunk
                  const float* __restrict__ Whh,   // [8,512,128]
                  const float* __restrict__ bias,  // [8,512]
                  float* __restrict__ out,         // [32,512,1024]
                  float* __restrict__ state,       // 4 x [32,8,128]
                  int t0, int tch, int first) {
  int blk = blockIdx.x;
  int b = blk >> 3, h = blk & 7;
  int t = threadIdx.x;
  int w = t >> 6;             // wave 0..7
  int l = t & 63;             // lane
  int q = w >> 1;             // col-slice / pair 0..3
  int em = (w & 1) * 64 + l;  // matvec output element 0..127
  int eg = q * 32 + (l & 31); // gate element this thread maintains

  __shared__ __align__(16) float part[2][128 * 20];  // 20 KB

  // weights: wreg[g*32+c] = Whh[h][g*128+em][32q+c]
  float wreg[128];
  {
    const float* wb = Whh + (size_t)h * 65536 + (size_t)q * 32;
#pragma unroll
    for (int g = 0; g < 4; ++g) {
      const float4* wp = (const float4*)(wb + (size_t)(g * 128 + em) * 128);
#pragma unroll
      for (int c4 = 0; c4 < 8; ++c4) {
        float4 v = wp[c4];
        wreg[g * 32 + c4 * 4 + 0] = v.x;
        wreg[g * 32 + c4 * 4 + 1] = v.y;
        wreg[g * 32 + c4 * 4 + 2] = v.z;
        wreg[g * 32 + c4 * 4 + 3] = v.w;
      }
    }
  }
#pragma unroll
  for (int i = 0; i < 128; ++i)
    asm volatile("" : "+v"(wreg[i]));  // opaque def: keep resident

  int si = (b * 8 + h) * 128 + eg;
  float hreg = 0.f, c_r = 0.f, n_r = 0.f, m_r = 0.f;
  if (!first) {
    hreg = state[si];
    c_r = state[32768 + si];
    m_r = state[65536 + si];
    n_r = state[98304 + si];
  }
  float bj0 = bias[h * 512 + eg];
  float bj1 = bias[h * 512 + 128 + eg];
  float bj2 = bias[h * 512 + 256 + eg];
  float bj3 = bias[h * 512 + 384 + eg];

  const float* gpb = G + (size_t)(b * tch) * 4096 + h * 512 + eg;
  float* op = out + ((size_t)b * 512 + t0) * 1024 + h * 128 + eg;
  bool writer = ((w & 1) == 0) && (l < 32);

  int ebase = em * 20 + q * 4;   // write slot (no XOR)
  int rb0 = eg * 20 + 0;
  int rb1 = eg * 20 + 4;
  int rb2 = eg * 20 + 8;
  int rb3 = eg * 20 + 12;

  // G for step 0 (exposed once; every later step is prefetched +1 ahead)
  float g0 = gpb[0], g1 = gpb[128], g2 = gpb[256], g3 = gpb[384];

  for (int s = 0; s < tch; ++s) {
    // prefetch G for step s+1 (consumed at END of iteration s+1)
    float gn0 = 0.f, gn1 = 0.f, gn2 = 0.f, gn3 = 0.f;
    if (s + 1 < tch) {
      const float* gr = gpb + (size_t)(s + 1) * 4096;
      gn0 = gr[0]; gn1 = gr[128]; gn2 = gr[256]; gn3 = gr[384];
    }

    // ---- matvec: h broadcast via readlane (VALU), no LDS ----
    float a0 = 0.f, a1 = 0.f, a2 = 0.f, a3 = 0.f;
    int hbits = __float_as_int(hreg);
#pragma unroll
    for (int c = 0; c < 32; ++c) {
      float hs = __int_as_float(__builtin_amdgcn_readlane(hbits, c));
      a0 = fmaf(wreg[c], hs, a0);
      a1 = fmaf(wreg[32 + c], hs, a1);
      a2 = fmaf(wreg[64 + c], hs, a2);
      a3 = fmaf(wreg[96 + c], hs, a3);
    }
    float4 pv = {a0, a1, a2, a3};
    *(float4*)&part[s & 1][ebase] = pv;
    __syncthreads();

    // ---- gate: all waves, redundant per (lane-half x pair) ----
    float4 p0 = *(const float4*)&part[s & 1][rb0];
    float4 p1 = *(const float4*)&part[s & 1][rb1];
    float4 p2 = *(const float4*)&part[s & 1][rb2];
    float4 p3 = *(const float4*)&part[s & 1][rb3];
    float iv = bj0 + g0 + ((p0.x + p1.x) + (p2.x + p3.x));
    float fv = bj1 + g1 + ((p0.y + p1.y) + (p2.y + p3.y));
    float zv = bj2 + g2 + ((p0.z + p1.z) + (p2.z + p3.z));
    float ov = bj3 + g3 + ((p0.w + p1.w) + (p2.w + p3.w));
    float e2 = __expf(2.f * zv);
    float zt = 1.f - 2.f * __builtin_amdgcn_rcpf(e2 + 1.f);   // tanh
    float og = __builtin_amdgcn_rcpf(1.f + __expf(-ov));      // sigmoid
    float mn = fmaxf(fv + m_r, iv);
    float ie = __expf(iv - mn);
    float fe = __expf(fv + m_r - mn);
    c_r = fe * c_r + ie * zt;
    n_r = fe * n_r + ie;
    m_r = mn;
    float hnew = og * c_r * __builtin_amdgcn_rcpf(n_r);
    hreg = hnew;
    if (writer) op[(size_t)s * 1024] = hnew;
    g0 = gn0; g1 = gn1; g2 = gn2; g3 = gn3;
  }

  if (writer) {
    state[si] = hreg;
    state[32768 + si] = c_r;
    state[65536 + si] = m_r;
    state[98304 + si] = n_r;
  }
}

// ---------------- launch ----------------
extern "C" void kernel_launch(void* const* d_in, const int* in_sizes, int n_in,
                              void* d_out, int out_size, void* d_ws, size_t ws_size,
                              hipStream_t stream) {
  const float* xs   = (const float*)d_in[0];
  const float* wif  = (const float*)d_in[1];
  const float* wzo  = (const float*)d_in[2];
  const float* whh  = (const float*)d_in[3];
  const float* bias = (const float*)d_in[4];
  float* out = (float*)d_out;

  char* ws = (char*)d_ws;
  unsigned short* Ahi = (unsigned short*)ws;                 // 33,554,432 B
  unsigned short* Alo = (unsigned short*)(ws + 33554432);    // 33,554,432 B
  unsigned short* Whi = (unsigned short*)(ws + 67108864);    //  8,388,608 B
  unsigned short* Wlo = (unsigned short*)(ws + 75497472);    //  8,388,608 B
  const size_t gbase = 83886080;

  // adaptive time chunk so G fits in ws
  int tch = 128;
  while (tch > 8 &&
         gbase + (size_t)32 * tch * 4096 * 4 + 524288 > ws_size)
    tch >>= 1;
  int ltch = (tch == 128) ? 7 : (tch == 64) ? 6 : (tch == 32) ? 5
             : (tch == 16) ? 4 : 3;

  float* G = (float*)(ws + gbase);
  float* state = (float*)(ws + gbase + (size_t)32 * tch * 4096 * 4);

  conv_x_split<<<16384, 256, 0, stream>>>(xs, Ahi, Alo, 4194304);
  conv_w_split<<<4096, 256, 0, stream>>>(wif, wzo, Whi, Wlo);

  for (int t0 = 0; t0 < 512; t0 += tch) {
    // grid: M-tiles = 32*tch/256, N-tiles = 4096/128
    gemm3_kernel<<<dim3((32 * tch) / 256, 32), 512, 0, stream>>>(
        Ahi, Alo, Whi, Wlo, G, t0, ltch);
    recur_kernel<<<256, 512, 0, stream>>>(G, whh, bias, out, state, t0, tch,
                                          t0 == 0);
  }
}

// Round 10
// 801.433 us; speedup vs baseline: 1.3182x; 1.0258x over previous
//
#include <hip/hip_runtime.h>
#include <hip/hip_bf16.h>
#include <stdint.h>

// Problem dims
#define B_SZ 32
#define T_SZ 512
#define I_SZ 1024
#define H_SZ 8
#define HS_SZ 128

typedef __attribute__((ext_vector_type(8))) short short8;
typedef __attribute__((ext_vector_type(4))) float f32x4;
typedef __attribute__((ext_vector_type(2))) float f32x2;

// ---------------- fp32 <-> bf16 helpers ----------------
static __device__ __forceinline__ unsigned short f2bf(float f) {
  union { float f; unsigned int u; } c; c.f = f;
  unsigned int u = c.u;
  unsigned int r = (u + 0x7fffu + ((u >> 16) & 1u)) >> 16;
  return (unsigned short)r;
}
static __device__ __forceinline__ float bf2f(unsigned short s) {
  union { unsigned int u; float f; } c; c.u = ((unsigned int)s) << 16;
  return c.f;
}
static __device__ __forceinline__ void split2(float x, unsigned short& hi,
                                              unsigned short& lo) {
  hi = f2bf(x);
  lo = f2bf(x - bf2f(hi));
}

__global__ void conv_x_split(const float* __restrict__ x,
                             unsigned short* __restrict__ ohi,
                             unsigned short* __restrict__ olo, int n4) {
  int i = blockIdx.x * blockDim.x + threadIdx.x;
  if (i >= n4) return;
  float4 v = ((const float4*)x)[i];
  ushort4 h, l;
  split2(v.x, h.x, l.x);
  split2(v.y, h.y, l.y);
  split2(v.z, h.z, l.z);
  split2(v.w, h.w, l.w);
  ((ushort4*)ohi)[i] = h;
  ((ushort4*)olo)[i] = l;
}

// Combined weight Wc[4096][1024], row n = h*512 + k4:
//   k4 in [0,256)   -> weight_if[h][k4][:]      (i rows then f rows)
//   k4 in [256,512) -> weight_zo[h][k4-256][:]  (z rows then o rows)
__global__ void conv_w_split(const float* __restrict__ wif,
                             const float* __restrict__ wzo,
                             unsigned short* __restrict__ ohi,
                             unsigned short* __restrict__ olo) {
  int i = blockIdx.x * blockDim.x + threadIdx.x;  // float4 index
  int flat = i * 4;
  int n = flat >> 10;
  int col = flat & 1023;
  int h = n >> 9, k4 = n & 511;
  const float* src = (k4 < 256)
                         ? (wif + ((size_t)(h * 256 + k4) * 1024 + col))
                         : (wzo + ((size_t)(h * 256 + (k4 - 256)) * 1024 + col));
  float4 v = *(const float4*)src;
  ushort4 hh, ll;
  split2(v.x, hh.x, ll.x);
  split2(v.y, hh.y, ll.y);
  split2(v.z, hh.z, ll.z);
  split2(v.w, hh.w, ll.w);
  ((ushort4*)ohi)[i] = hh;
  ((ushort4*)olo)[i] = ll;
}

// ---------------- GEMM (round-9 structure, unchanged) ----------------
// 256x128 tile, BK=32, 8 waves, double-buffered LDS, counted vmcnt,
// raw s_barrier, slot-XOR swizzle, setprio. 3-pass split-bf16.
__device__ __forceinline__ void gld_lds16(const void* g, void* l) {
  __builtin_amdgcn_global_load_lds(
      (const __attribute__((address_space(1))) void*)g,
      (__attribute__((address_space(3))) void*)l, 16, 0, 0);
}

__global__ __launch_bounds__(512)
void gemm3_kernel(const unsigned short* __restrict__ Ahi,
                  const unsigned short* __restrict__ Alo,
                  const unsigned short* __restrict__ Whi,
                  const unsigned short* __restrict__ Wlo,
                  float* __restrict__ G, int t0, int ltch) {
  __shared__ short lds2[2][24576];  // 2 x 48 KB

  const int tid = threadIdx.x;
  const int lane = tid & 63, wv = tid >> 6;
  const int wm = wv >> 1, wn = wv & 1;   // 4 M-waves x 2 N-waves
  const int bx = blockIdx.x, by = blockIdx.y;
  const int l15 = lane & 15, kg = lane >> 4;
  const int tchm = (1 << ltch) - 1;

  // staging source pointers (6 units of 16 B per thread per K-step)
  const unsigned short* gsrc[6];
#pragma unroll
  for (int t = 0; t < 6; ++t) {
    int u = tid + t * 512;
    int j = u & 3;
    if (t < 4) {
      int r = (u >> 2) & 255;
      int gslot = j ^ ((r >> 1) & 3);
      int cr = bx * 256 + r;
      size_t xsrow = (size_t)(cr >> ltch) * 512 + t0 + (cr & tchm);
      gsrc[t] = ((t < 2) ? Ahi : Alo) + xsrow * 1024 + gslot * 8;
    } else {
      int r = (u >> 2) & 127;
      int gslot = j ^ ((r >> 1) & 3);
      size_t wr = (size_t)by * 128 + r;
      gsrc[t] = ((t == 4) ? Whi : Wlo) + wr * 1024 + gslot * 8;
    }
  }

  // frag read offsets (shorts), swizzled slot per row
  int offa[4], offw[4];
#pragma unroll
  for (int mi = 0; mi < 4; ++mi) {
    int r = wm * 64 + mi * 16 + l15;
    offa[mi] = r * 32 + (kg ^ ((r >> 1) & 3)) * 8;
  }
#pragma unroll
  for (int ni = 0; ni < 4; ++ni) {
    int r = wn * 64 + ni * 16 + l15;
    offw[ni] = r * 32 + (kg ^ ((r >> 1) & 3)) * 8;
  }

  f32x4 zero4 = {0.f, 0.f, 0.f, 0.f};
  f32x4 acc[4][4];
#pragma unroll
  for (int mi = 0; mi < 4; ++mi)
#pragma unroll
    for (int ni = 0; ni < 4; ++ni) acc[mi][ni] = zero4;

  // prologue: stage K-steps 0 and 1
#pragma unroll
  for (int t = 0; t < 6; ++t)
    gld_lds16(gsrc[t], &lds2[0][(wv * 64 + t * 512) * 8]);
#pragma unroll
  for (int t = 0; t < 6; ++t)
    gld_lds16(gsrc[t] + 32, &lds2[1][(wv * 64 + t * 512) * 8]);
  asm volatile("s_waitcnt vmcnt(6)" : : : "memory");
  __builtin_amdgcn_s_barrier();

  for (int ks = 0; ks < 32; ++ks) {
    const short* bp = &lds2[ks & 1][0];

    short8 ah[4], wh4[4], al[4], wl4[4];
#pragma unroll
    for (int mi = 0; mi < 4; ++mi) ah[mi] = *(const short8*)(bp + offa[mi]);
#pragma unroll
    for (int ni = 0; ni < 4; ++ni)
      wh4[ni] = *(const short8*)(bp + 16384 + offw[ni]);

    __builtin_amdgcn_s_setprio(1);
#pragma unroll
    for (int mi = 0; mi < 4; ++mi)
#pragma unroll
      for (int ni = 0; ni < 4; ++ni)
        acc[mi][ni] = __builtin_amdgcn_mfma_f32_16x16x32_bf16(
            ah[mi], wh4[ni], acc[mi][ni], 0, 0, 0);

#pragma unroll
    for (int mi = 0; mi < 4; ++mi)
      al[mi] = *(const short8*)(bp + 8192 + offa[mi]);
#pragma unroll
    for (int mi = 0; mi < 4; ++mi)
#pragma unroll
      for (int ni = 0; ni < 4; ++ni)
        acc[mi][ni] = __builtin_amdgcn_mfma_f32_16x16x32_bf16(
            al[mi], wh4[ni], acc[mi][ni], 0, 0, 0);

#pragma unroll
    for (int ni = 0; ni < 4; ++ni)
      wl4[ni] = *(const short8*)(bp + 20480 + offw[ni]);
#pragma unroll
    for (int mi = 0; mi < 4; ++mi)
#pragma unroll
      for (int ni = 0; ni < 4; ++ni)
        acc[mi][ni] = __builtin_amdgcn_mfma_f32_16x16x32_bf16(
            ah[mi], wl4[ni], acc[mi][ni], 0, 0, 0);
    __builtin_amdgcn_s_setprio(0);

    asm volatile("s_waitcnt lgkmcnt(0)" : : : "memory");
    __builtin_amdgcn_sched_barrier(0);
    __builtin_amdgcn_s_barrier();

    if (ks + 2 < 32) {
#pragma unroll
      for (int t = 0; t < 6; ++t)
        gld_lds16(gsrc[t] + (ks + 2) * 32,
                  &lds2[ks & 1][(wv * 64 + t * 512) * 8]);
      asm volatile("s_waitcnt vmcnt(6)" : : : "memory");
    } else {
      asm volatile("s_waitcnt vmcnt(0)" : : : "memory");
    }
    __builtin_amdgcn_s_barrier();
  }

  // epilogue: C/D layout (m89): col = lane&15, row = (lane>>4)*4+reg
#pragma unroll
  for (int mi = 0; mi < 4; ++mi)
#pragma unroll
    for (int ni = 0; ni < 4; ++ni)
#pragma unroll
      for (int r = 0; r < 4; ++r) {
        int grow = bx * 256 + wm * 64 + mi * 16 + kg * 4 + r;
        int gcol = by * 128 + wn * 64 + ni * 16 + l15;
        G[(size_t)grow * 4096 + gcol] = acc[mi][ni][r];
      }
}

// ---------------- Recurrence (round 10: v_pk_fma_f32 matvec) ----------------
// Structure = round 8/9 (register weights, readlane h-broadcast, stride-20
// b128 partial exchange, +1-step G prefetch, 1 barrier/step). Change: the
// matvec uses packed dual-rate fp32 FMA — weights as 64 f32x2 pairs, h-pair
// built from two readlane SGPRs packed into an SGPR pair ("s" asm operand;
// SALU packing runs off the VALU pipe). 128 fma -> 64 pk_fma: ~40% fewer
// VALU issues in the dominant phase. Same fp32 arithmetic -> same absmax.
__global__ __launch_bounds__(512, 1)
void recur_kernel(const float* __restrict__ G,     // [32*tch, 4096] chunk
                  const float* __restrict__ Whh,   // [8,512,128]
                  const float* __restrict__ bias,  // [8,512]
                  float* __restrict__ out,         // [32,512,1024]
                  float* __restrict__ state,       // 4 x [32,8,128]
                  int t0, int tch, int first) {
  int blk = blockIdx.x;
  int b = blk >> 3, h = blk & 7;
  int t = threadIdx.x;
  int w = t >> 6;             // wave 0..7
  int l = t & 63;             // lane
  int q = w >> 1;             // col-slice / pair 0..3
  int em = (w & 1) * 64 + l;  // matvec output element 0..127
  int eg = q * 32 + (l & 31); // gate element this thread maintains

  __shared__ __align__(16) float part[2][128 * 20];  // 20 KB

  // weights as pairs: w2[g*16+c2] = {W[h][g*128+em][32q+2c2], ..[32q+2c2+1]}
  f32x2 w2[64];
  {
    const float* wb = Whh + (size_t)h * 65536 + (size_t)q * 32;
#pragma unroll
    for (int g = 0; g < 4; ++g) {
      const float4* wp = (const float4*)(wb + (size_t)(g * 128 + em) * 128);
#pragma unroll
      for (int c4 = 0; c4 < 8; ++c4) {
        float4 v = wp[c4];
        f32x2 lo2 = {v.x, v.y};
        f32x2 hi2 = {v.z, v.w};
        w2[g * 16 + 2 * c4] = lo2;
        w2[g * 16 + 2 * c4 + 1] = hi2;
      }
    }
  }
#pragma unroll
  for (int i = 0; i < 64; ++i)
    asm volatile("" : "+v"(w2[i]));  // opaque def: keep resident

  int si = (b * 8 + h) * 128 + eg;
  float hreg = 0.f, c_r = 0.f, n_r = 0.f, m_r = 0.f;
  if (!first) {
    hreg = state[si];
    c_r = state[32768 + si];
    m_r = state[65536 + si];
    n_r = state[98304 + si];
  }
  float bj0 = bias[h * 512 + eg];
  float bj1 = bias[h * 512 + 128 + eg];
  float bj2 = bias[h * 512 + 256 + eg];
  float bj3 = bias[h * 512 + 384 + eg];

  const float* gpb = G + (size_t)(b * tch) * 4096 + h * 512 + eg;
  float* op = out + ((size_t)b * 512 + t0) * 1024 + h * 128 + eg;
  bool writer = ((w & 1) == 0) && (l < 32);

  int ebase = em * 20 + q * 4;   // write slot
  int rb0 = eg * 20 + 0;
  int rb1 = eg * 20 + 4;
  int rb2 = eg * 20 + 8;
  int rb3 = eg * 20 + 12;

  // G for step 0 (exposed once; later steps prefetched +1 ahead)
  float g0 = gpb[0], g1 = gpb[128], g2 = gpb[256], g3 = gpb[384];

  for (int s = 0; s < tch; ++s) {
    // prefetch G for step s+1 (consumed at END of iteration s+1)
    float gn0 = 0.f, gn1 = 0.f, gn2 = 0.f, gn3 = 0.f;
    if (s + 1 < tch) {
      const float* gr = gpb + (size_t)(s + 1) * 4096;
      gn0 = gr[0]; gn1 = gr[128]; gn2 = gr[256]; gn3 = gr[384];
    }

    // ---- matvec: packed fp32 FMA; h pairs via readlane->SGPR pair ----
    f32x2 a0 = {0.f, 0.f}, a1 = {0.f, 0.f}, a2 = {0.f, 0.f}, a3 = {0.f, 0.f};
    int hbits = __float_as_int(hreg);
#pragma unroll
    for (int c2 = 0; c2 < 16; ++c2) {
      unsigned int hlo = (unsigned int)__builtin_amdgcn_readlane(hbits, 2 * c2);
      unsigned int hhi =
          (unsigned int)__builtin_amdgcn_readlane(hbits, 2 * c2 + 1);
      uint64_t h2 = ((uint64_t)hhi << 32) | (uint64_t)hlo;
      asm("v_pk_fma_f32 %0, %1, %2, %0" : "+v"(a0) : "v"(w2[c2]), "s"(h2));
      asm("v_pk_fma_f32 %0, %1, %2, %0" : "+v"(a1) : "v"(w2[16 + c2]), "s"(h2));
      asm("v_pk_fma_f32 %0, %1, %2, %0" : "+v"(a2) : "v"(w2[32 + c2]), "s"(h2));
      asm("v_pk_fma_f32 %0, %1, %2, %0" : "+v"(a3) : "v"(w2[48 + c2]), "s"(h2));
    }
    float4 pv = {a0.x + a0.y, a1.x + a1.y, a2.x + a2.y, a3.x + a3.y};
    *(float4*)&part[s & 1][ebase] = pv;
    __syncthreads();

    // ---- gate: all waves, redundant per (lane-half x pair) ----
    float4 p0 = *(const float4*)&part[s & 1][rb0];
    float4 p1 = *(const float4*)&part[s & 1][rb1];
    float4 p2 = *(const float4*)&part[s & 1][rb2];
    float4 p3 = *(const float4*)&part[s & 1][rb3];
    float iv = bj0 + g0 + ((p0.x + p1.x) + (p2.x + p3.x));
    float fv = bj1 + g1 + ((p0.y + p1.y) + (p2.y + p3.y));
    float zv = bj2 + g2 + ((p0.z + p1.z) + (p2.z + p3.z));
    float ov = bj3 + g3 + ((p0.w + p1.w) + (p2.w + p3.w));
    float e2 = __expf(2.f * zv);
    float zt = 1.f - 2.f * __builtin_amdgcn_rcpf(e2 + 1.f);   // tanh
    float og = __builtin_amdgcn_rcpf(1.f + __expf(-ov));      // sigmoid
    float mn = fmaxf(fv + m_r, iv);
    float ie = __expf(iv - mn);
    float fe = __expf(fv + m_r - mn);
    c_r = fe * c_r + ie * zt;
    n_r = fe * n_r + ie;
    m_r = mn;
    float hnew = og * c_r * __builtin_amdgcn_rcpf(n_r);
    hreg = hnew;
    if (writer) op[(size_t)s * 1024] = hnew;
    g0 = gn0; g1 = gn1; g2 = gn2; g3 = gn3;
  }

  if (writer) {
    state[si] = hreg;
    state[32768 + si] = c_r;
    state[65536 + si] = m_r;
    state[98304 + si] = n_r;
  }
}

// ---------------- launch ----------------
extern "C" void kernel_launch(void* const* d_in, const int* in_sizes, int n_in,
                              void* d_out, int out_size, void* d_ws, size_t ws_size,
                              hipStream_t stream) {
  const float* xs   = (const float*)d_in[0];
  const float* wif  = (const float*)d_in[1];
  const float* wzo  = (const float*)d_in[2];
  const float* whh  = (const float*)d_in[3];
  const float* bias = (const float*)d_in[4];
  float* out = (float*)d_out;

  char* ws = (char*)d_ws;
  unsigned short* Ahi = (unsigned short*)ws;                 // 33,554,432 B
  unsigned short* Alo = (unsigned short*)(ws + 33554432);    // 33,554,432 B
  unsigned short* Whi = (unsigned short*)(ws + 67108864);    //  8,388,608 B
  unsigned short* Wlo = (unsigned short*)(ws + 75497472);    //  8,388,608 B
  const size_t gbase = 83886080;

  // adaptive time chunk so G fits in ws — start at 512 (single launch pair)
  int tch = 512;
  while (tch > 8 &&
         gbase + (size_t)32 * tch * 4096 * 4 + 524288 > ws_size)
    tch >>= 1;
  int ltch = 0;
  while ((1 << (ltch + 1)) <= tch) ++ltch;

  float* G = (float*)(ws + gbase);
  float* state = (float*)(ws + gbase + (size_t)32 * tch * 4096 * 4);

  conv_x_split<<<16384, 256, 0, stream>>>(xs, Ahi, Alo, 4194304);
  conv_w_split<<<4096, 256, 0, stream>>>(wif, wzo, Whi, Wlo);

  for (int t0 = 0; t0 < 512; t0 += tch) {
    gemm3_kernel<<<dim3((32 * tch) / 256, 32), 512, 0, stream>>>(
        Ahi, Alo, Whi, Wlo, G, t0, ltch);
    recur_kernel<<<256, 512, 0, stream>>>(G, whh, bias, out, state, t0, tch,
                                          t0 == 0);
  }
}